// Round 14
// baseline (220.832 us; speedup 1.0000x reference)
//
#include <hip/hip_runtime.h>
#include <hip/hip_bf16.h>
#include <cstdint>

typedef __bf16 bf16x8 __attribute__((ext_vector_type(8)));
typedef float f32x4 __attribute__((ext_vector_type(4)));
typedef float f32x16 __attribute__((ext_vector_type(16)));

__device__ __forceinline__ float bf2f(unsigned short u) {
  union { unsigned int i; float f; } x; x.i = ((unsigned int)u) << 16; return x.f;
}
__device__ __forceinline__ unsigned short f2bf(float f) {
  __hip_bfloat16 h = __float2bfloat16(f);
  return __builtin_bit_cast(unsigned short, h);
}

__device__ __forceinline__ void gload_lds16(const void* g, void* l) {
  auto gp = reinterpret_cast<__attribute__((address_space(1))) char*>(
      reinterpret_cast<uintptr_t>(g));
  auto lp = reinterpret_cast<__attribute__((address_space(3))) char*>(
      reinterpret_cast<uintptr_t>(l));
  __builtin_amdgcn_global_load_lds(gp, lp, 16, 0, 0);
}

// T1: bijective XCD-aware block swizzle (requires total blocks % 8 == 0)
__device__ __forceinline__ void xcd_swz(int& bx, int& by, int& bz) {
  const int gx = gridDim.x, gy = gridDim.y;
  const int n = gx * gy * (int)gridDim.z;
  int lin = blockIdx.x + gx * (blockIdx.y + gy * blockIdx.z);
  lin = (lin & 7) * (n >> 3) + (lin >> 3);
  bx = lin % gx; lin /= gx;
  by = lin % gy; bz = lin / gy;
}

// ---------- fp32 -> bf16 ----------
__global__ __launch_bounds__(256) void cvt_f32_to_bf16(
    const float* __restrict__ in, unsigned short* __restrict__ out, long n4) {
  long i = (long)blockIdx.x * 256 + threadIdx.x;
  if (i >= n4) return;
  const float4 v = reinterpret_cast<const float4*>(in)[i];
  ushort4 o;
  o.x = f2bf(v.x); o.y = f2bf(v.y); o.z = f2bf(v.z); o.w = f2bf(v.w);
  reinterpret_cast<ushort4*>(out)[i] = o;
}

// ---------- all 4 weight transposes + bias concat in one launch ----------
__global__ void transpose_w4(const float* __restrict__ w0,
                             const float* __restrict__ w1,
                             const float* __restrict__ w2,
                             const float* __restrict__ w3,
                             const float* __restrict__ b0,
                             const float* __restrict__ b1,
                             const float* __restrict__ b2,
                             unsigned short* __restrict__ out,
                             float* __restrict__ bqkv) {
  const int z = blockIdx.z;
  const float* in = (z == 0) ? w0 : (z == 1) ? w1 : (z == 2) ? w2 : w3;
  out += (size_t)z * 1024 * 1024;
  if (z < 3 && blockIdx.x == 0 && blockIdx.y == 0) {
    const float* src = (z == 0) ? b0 : (z == 1) ? b1 : b2;
    const int i = threadIdx.y * 32 + threadIdx.x;
    bqkv[z * 1024 + i] = src[i];
  }
  __shared__ float tile[32][33];
  const int c0 = blockIdx.x * 32, r0 = blockIdx.y * 32;
  tile[threadIdx.y][threadIdx.x] =
      in[(size_t)(r0 + threadIdx.y) * 1024 + c0 + threadIdx.x];
  __syncthreads();
  out[(size_t)(c0 + threadIdx.y) * 1024 + r0 + threadIdx.x] =
      f2bf(tile[threadIdx.x][threadIdx.y]);
}

// =====================================================================
// gemm_hi: R11 structure (128x128 tile, 4 waves 2Mx2N, per-wave 64x64,
// BK=64, single-buffered 32KB LDS, XOR swizzle both sides, plain
// __syncthreads, (256,4)) with the MFMA core ported to 32x32x16_bf16:
// per wave 2x2 tiles of 32x32, 16 MFMA/K-tile @8cyc (vs 32 @4.85) --
// ~17% fewer MFMA cycles, half the issue slots.
// Layouts: C/D (nominal) col=lane&31(N), row=(reg&3)+8*(reg>>2)+
// 4*(lane>>5) (M)  [m74/m101-verified]. A/B input: row=lane&31,
// k=(lane>>5)*8+j contiguous (contiguous-8 proven by the working
// 16x16x32 kernels R1-R11).
// LAUNCH BOUNDS RULE (R8+R12): never cap VGPR below 128 -- (256,4) only.
// ROWXCD (QKV): row-grouped XCD map, grid (24,64).
// VSPLIT (QKV): n0>=2048 cols are V -> vt[b][d][s] transposed (nominal
// MFMA: M from regs -> vec4 along s); else swapped MFMA (N from regs ->
// vec4 C stores).
// EXPOUT (scores): C = exp(acc*scale) + per-wave partial row-sums into
// psum[b][row][bx*2+wn] (32 slots/row).
// DIVSUM (PV): C = acc / sum(psum[b][row][0..32]).
// =====================================================================
template <typename OutT, bool HAS_BIAS, bool VSPLIT, bool EXPOUT, bool DIVSUM,
          bool ROWXCD>
__global__ __launch_bounds__(256, 4) void gemm_hi(
    const unsigned short* __restrict__ A,
    const unsigned short* __restrict__ Bt,
    OutT* __restrict__ C,
    const float* __restrict__ bias,   // bias | psum-base (DIVSUM)
    unsigned short* __restrict__ vt,  // Vt (VSPLIT)
    float* __restrict__ psum,         // partial row-sums (EXPOUT)
    int K, int lda, int ldb, int ldc, float scale,
    long sA, long sB, long sC) {
  int bx, by, bz;
  if constexpr (ROWXCD) {
    const int lin = blockIdx.x + 24 * blockIdx.y;
    const int xcd = lin & 7, idx = lin >> 3;  // idx in 0..191
    by = xcd + ((idx / 24) << 3);
    bx = idx % 24;
    bz = 0;
  } else {
    xcd_swz(bx, by, bz);
  }
  A  += (long)bz * sA;
  Bt += (long)bz * sB;
  C  += (long)bz * sC;
  const int n0 = bx << 7;
  const int m0 = by << 7;
  __shared__ __attribute__((aligned(16))) unsigned short As[128 * 64];
  __shared__ __attribute__((aligned(16))) unsigned short Bs[128 * 64];
  const int t = threadIdx.x;
  const int lane = t & 63;
  const int w = t >> 6;
  const int wm = w >> 1, wn = w & 1;
  const unsigned short* gA = A + (size_t)m0 * lda;
  const unsigned short* gB = Bt + (size_t)n0 * ldb;
  const int NT = K >> 6;

  const int srow = lane >> 3;
  const int scol = ((lane & 7) ^ srow) << 3;

  f32x16 acc[2][2];
#pragma unroll
  for (int i = 0; i < 2; ++i)
#pragma unroll
    for (int j = 0; j < 2; ++j)
#pragma unroll
      for (int e = 0; e < 16; ++e) acc[i][j][e] = 0.f;

  for (int kt = 0; kt < NT; ++kt) {
    const unsigned short* pA = gA + (size_t)kt * 64;
    const unsigned short* pB = gB + (size_t)kt * 64;
#pragma unroll
    for (int i = 0; i < 4; ++i) {
      const int r0 = (w << 3) + (i << 5);
      gload_lds16(pA + (size_t)(r0 + srow) * lda + scol, As + r0 * 64);
      gload_lds16(pB + (size_t)(r0 + srow) * ldb + scol, Bs + r0 * 64);
    }
    __syncthreads();

#pragma unroll
    for (int ks = 0; ks < 4; ++ks) {
      bf16x8 af[2], bg[2];
      const int ch = ((ks << 1) + (lane >> 5)) ^ (lane & 7);
#pragma unroll
      for (int mt = 0; mt < 2; ++mt) {
        const int row = (wm << 6) + (mt << 5) + (lane & 31);
        af[mt] = *reinterpret_cast<const bf16x8*>(As + row * 64 + (ch << 3));
      }
#pragma unroll
      for (int nt = 0; nt < 2; ++nt) {
        const int row = (wn << 6) + (nt << 5) + (lane & 31);
        bg[nt] = *reinterpret_cast<const bf16x8*>(Bs + row * 64 + (ch << 3));
      }
#pragma unroll
      for (int mt = 0; mt < 2; ++mt)
#pragma unroll
        for (int nt = 0; nt < 2; ++nt) {
          if constexpr (VSPLIT) {
            acc[mt][nt] = __builtin_amdgcn_mfma_f32_32x32x16_bf16(
                af[mt], bg[nt], acc[mt][nt], 0, 0, 0);
          } else {
            acc[mt][nt] = __builtin_amdgcn_mfma_f32_32x32x16_bf16(
                bg[nt], af[mt], acc[mt][nt], 0, 0, 0);
          }
        }
    }
    __syncthreads();
  }

  if constexpr (VSPLIT) {
    // nominal D: N = lane&31, M = (reg&3)+8*(reg>>2)+4*(lane>>5)
    const int cbase = n0 + (wn << 6) + (lane & 31);
    const int rbase = m0 + (wm << 6) + ((lane >> 5) << 2);
    if (n0 >= 2048) {
      const int b = m0 >> 11;
#pragma unroll
      for (int nt = 0; nt < 2; ++nt) {
        const int col = cbase + (nt << 5);
        const float bb = HAS_BIAS ? bias[col] : 0.f;
        const int d = col - 2048;
#pragma unroll
        for (int mt = 0; mt < 2; ++mt) {
#pragma unroll
          for (int q = 0; q < 4; ++q) {
            const int s = (rbase + (mt << 5) + (q << 3)) & 2047;
            ushort4 o;
            o.x = f2bf(acc[mt][nt][4 * q + 0] * scale + bb);
            o.y = f2bf(acc[mt][nt][4 * q + 1] * scale + bb);
            o.z = f2bf(acc[mt][nt][4 * q + 2] * scale + bb);
            o.w = f2bf(acc[mt][nt][4 * q + 3] * scale + bb);
            *reinterpret_cast<ushort4*>(
                vt + (((size_t)b << 10) + d) * 2048 + s) = o;
          }
        }
      }
    } else {
#pragma unroll
      for (int nt = 0; nt < 2; ++nt) {
        const int col = cbase + (nt << 5);
        const float bb = HAS_BIAS ? bias[col] : 0.f;
#pragma unroll
        for (int mt = 0; mt < 2; ++mt) {
#pragma unroll
          for (int q = 0; q < 4; ++q) {
#pragma unroll
            for (int j = 0; j < 4; ++j) {
              const int row = rbase + (mt << 5) + (q << 3) + j;
              C[(size_t)row * ldc + col] =
                  (OutT)f2bf(acc[mt][nt][4 * q + j] * scale + bb);
            }
          }
        }
      }
    }
  } else {
    // swapped D: M = lane&31, N = (reg&3)+8*(reg>>2)+4*(lane>>5)
    const int mbase = m0 + (wm << 6) + (lane & 31);
    const int nbase = n0 + (wn << 6) + ((lane >> 5) << 2);
#pragma unroll
    for (int mt = 0; mt < 2; ++mt) {
      const int row = mbase + (mt << 5);
      float inv = 1.f;
      if constexpr (DIVSUM) {
        const float* pr = bias + ((long)bz * 2048 + row) * 32;
        float s = 0.f;
#pragma unroll
        for (int q8 = 0; q8 < 8; ++q8) {
          const float4 sv = *reinterpret_cast<const float4*>(pr + q8 * 4);
          s += (sv.x + sv.y) + (sv.z + sv.w);
        }
        inv = 1.f / s;
      }
      float ps = 0.f;
#pragma unroll
      for (int nt = 0; nt < 2; ++nt) {
#pragma unroll
        for (int q = 0; q < 4; ++q) {
          const int col = nbase + (nt << 5) + (q << 3);
          const float a0 = acc[mt][nt][4 * q + 0];
          const float a1 = acc[mt][nt][4 * q + 1];
          const float a2 = acc[mt][nt][4 * q + 2];
          const float a3 = acc[mt][nt][4 * q + 3];
          if constexpr (EXPOUT) {
            const float e0 = __expf(a0 * scale);
            const float e1 = __expf(a1 * scale);
            const float e2 = __expf(a2 * scale);
            const float e3 = __expf(a3 * scale);
            ps += (e0 + e1) + (e2 + e3);
            ushort4 o;
            o.x = f2bf(e0); o.y = f2bf(e1); o.z = f2bf(e2); o.w = f2bf(e3);
            *reinterpret_cast<ushort4*>(&C[(size_t)row * ldc + col]) = o;
          } else if constexpr (DIVSUM) {
            ushort4 o;
            o.x = f2bf(a0 * inv);
            o.y = f2bf(a1 * inv);
            o.z = f2bf(a2 * inv);
            o.w = f2bf(a3 * inv);
            *reinterpret_cast<ushort4*>(&C[(size_t)row * ldc + col]) = o;
          } else {
            float4 bb = {0.f, 0.f, 0.f, 0.f};
            if (HAS_BIAS) bb = *reinterpret_cast<const float4*>(bias + col);
            if constexpr (sizeof(OutT) == 2) {
              ushort4 o;
              o.x = f2bf(a0 * scale + bb.x);
              o.y = f2bf(a1 * scale + bb.y);
              o.z = f2bf(a2 * scale + bb.z);
              o.w = f2bf(a3 * scale + bb.w);
              *reinterpret_cast<ushort4*>(&C[(size_t)row * ldc + col]) = o;
            } else {
              float4 o;
              o.x = a0 * scale + bb.x;
              o.y = a1 * scale + bb.y;
              o.z = a2 * scale + bb.z;
              o.w = a3 * scale + bb.w;
              *reinterpret_cast<float4*>(&C[(size_t)row * ldc + col]) = o;
            }
          }
        }
      }
      if constexpr (EXPOUT) {
        // lane l and l^32 share row; merge then lanes 0-31 store.
        ps += __shfl_xor(ps, 32, 64);
        if (lane < 32)
          psum[((long)bz * 2048 + row) * 32 + (bx << 1) + wn] = ps;
      }
    }
  }
}

// ---------- launch ----------
extern "C" void kernel_launch(void* const* d_in, const int* in_sizes, int n_in,
                              void* d_out, int out_size, void* d_ws, size_t ws_size,
                              hipStream_t stream) {
  (void)in_sizes; (void)n_in; (void)out_size; (void)ws_size;
  const float* x  = (const float*)d_in[0];
  const float* Wq = (const float*)d_in[1];
  const float* bq = (const float*)d_in[2];
  const float* Wk = (const float*)d_in[3];
  const float* bk = (const float*)d_in[4];
  const float* Wv = (const float*)d_in[5];
  const float* bv = (const float*)d_in[6];
  const float* Wo = (const float*)d_in[7];
  const float* bo = (const float*)d_in[8];
  float* out = (float*)d_out;

  constexpr int B = 4, S = 2048, D = 1024;
  constexpr long BS = (long)B * S;  // 8192
  constexpr size_t MB = 1ull << 20;
  char* ws = (char*)d_ws;
  unsigned short* xb   = (unsigned short*)(ws + 0);        // 16MB (dead after QKV)
  unsigned short* Wall = (unsigned short*)(ws + 16 * MB);  // 8MB [4][1024][1024]
  float*          bqkv = (float*)(ws + 24 * MB);           // 12KB
  float*          psum = (float*)(ws + 24 * MB + 65536);   // 1MB [4][2048][32]
  unsigned short* QKVc = (unsigned short*)(ws + 26 * MB);  // 32MB [8192][2048] Q|K
  unsigned short* Vt   = (unsigned short*)(ws + 58 * MB);  // 16MB [4][1024][2048]
  unsigned short* Sc   = (unsigned short*)(ws + 74 * MB);  // 32MB exp-scores
  unsigned short* AO   = (unsigned short*)(ws + 0);        // 16MB (over xb)

  const float scale = 0.03125f;  // 1/sqrt(1024)

  cvt_f32_to_bf16<<<(BS * D / 4 + 255) / 256, 256, 0, stream>>>(x, xb, BS * D / 4);
  transpose_w4<<<dim3(32, 32, 4), dim3(32, 32), 0, stream>>>(
      Wq, Wk, Wv, Wo, bq, bk, bv, Wall, bqkv);

  // fused QKV projection (row-grouped XCD map): Q|K -> QKVc, V -> Vt^T
  gemm_hi<unsigned short, true, true, false, false, true>
      <<<dim3(24, 64, 1), 256, 0, stream>>>(
      xb, Wall, QKVc, bqkv, Vt, nullptr, D, D, D, 2048, 1.f, 0, 0, 0);

  // exp-scores[b] = exp(scale * Q@K^T); per-wave partial row-sums -> psum
  gemm_hi<unsigned short, false, false, true, false, false>
      <<<dim3(16, 16, 4), 256, 0, stream>>>(
      QKVc + 0, QKVc + 1024, Sc, nullptr, nullptr, psum, D, 2048, 2048, S,
      scale, (long)S * 2048, (long)S * 2048, (long)S * S);

  // attn_out[b] = (expS[b] @ V[b]) / rowsum  via Vt
  gemm_hi<unsigned short, false, false, false, true, false>
      <<<dim3(8, 16, 4), 256, 0, stream>>>(
      Sc, Vt, AO, psum, nullptr, nullptr, S, S, S, D, 1.f,
      (long)S * S, (long)D * S, (long)S * D);

  // out = AO @ Wot^T + bo (fp32)
  gemm_hi<float, true, false, false, false, false>
      <<<dim3(8, 64, 1), 256, 0, stream>>>(
      AO, Wall + 3 * 1024 * 1024, out, bo, nullptr, nullptr, D, D, D, D, 1.f,
      0, 0, 0);
}

// Round 15
// 198.962 us; speedup vs baseline: 1.1099x; 1.1099x over previous
//
#include <hip/hip_runtime.h>
#include <hip/hip_bf16.h>
#include <cstdint>

typedef __bf16 bf16x8 __attribute__((ext_vector_type(8)));
typedef float f32x4 __attribute__((ext_vector_type(4)));

__device__ __forceinline__ float bf2f(unsigned short u) {
  union { unsigned int i; float f; } x; x.i = ((unsigned int)u) << 16; return x.f;
}
__device__ __forceinline__ unsigned short f2bf(float f) {
  __hip_bfloat16 h = __float2bfloat16(f);
  return __builtin_bit_cast(unsigned short, h);
}

__device__ __forceinline__ void gload_lds16(const void* g, void* l) {
  auto gp = reinterpret_cast<__attribute__((address_space(1))) char*>(
      reinterpret_cast<uintptr_t>(g));
  auto lp = reinterpret_cast<__attribute__((address_space(3))) char*>(
      reinterpret_cast<uintptr_t>(l));
  __builtin_amdgcn_global_load_lds(gp, lp, 16, 0, 0);
}

// T1: bijective XCD-aware block swizzle (requires total blocks % 8 == 0)
__device__ __forceinline__ void xcd_swz(int& bx, int& by, int& bz) {
  const int gx = gridDim.x, gy = gridDim.y;
  const int n = gx * gy * (int)gridDim.z;
  int lin = blockIdx.x + gx * (blockIdx.y + gy * blockIdx.z);
  lin = (lin & 7) * (n >> 3) + (lin >> 3);
  bx = lin % gx; lin /= gx;
  by = lin % gy; bz = lin / gy;
}

// ---------- fp32 -> bf16 ----------
__global__ __launch_bounds__(256) void cvt_f32_to_bf16(
    const float* __restrict__ in, unsigned short* __restrict__ out, long n4) {
  long i = (long)blockIdx.x * 256 + threadIdx.x;
  if (i >= n4) return;
  const float4 v = reinterpret_cast<const float4*>(in)[i];
  ushort4 o;
  o.x = f2bf(v.x); o.y = f2bf(v.y); o.z = f2bf(v.z); o.w = f2bf(v.w);
  reinterpret_cast<ushort4*>(out)[i] = o;
}

// ---------- all 4 weight transposes + bias concat in one launch ----------
__global__ void transpose_w4(const float* __restrict__ w0,
                             const float* __restrict__ w1,
                             const float* __restrict__ w2,
                             const float* __restrict__ w3,
                             const float* __restrict__ b0,
                             const float* __restrict__ b1,
                             const float* __restrict__ b2,
                             unsigned short* __restrict__ out,
                             float* __restrict__ bqkv) {
  const int z = blockIdx.z;
  const float* in = (z == 0) ? w0 : (z == 1) ? w1 : (z == 2) ? w2 : w3;
  out += (size_t)z * 1024 * 1024;
  if (z < 3 && blockIdx.x == 0 && blockIdx.y == 0) {
    const float* src = (z == 0) ? b0 : (z == 1) ? b1 : b2;
    const int i = threadIdx.y * 32 + threadIdx.x;
    bqkv[z * 1024 + i] = src[i];
  }
  __shared__ float tile[32][33];
  const int c0 = blockIdx.x * 32, r0 = blockIdx.y * 32;
  tile[threadIdx.y][threadIdx.x] =
      in[(size_t)(r0 + threadIdx.y) * 1024 + c0 + threadIdx.x];
  __syncthreads();
  out[(size_t)(c0 + threadIdx.y) * 1024 + r0 + threadIdx.x] =
      f2bf(tile[threadIdx.x][threadIdx.y]);
}

// =====================================================================
// gemm_hi (R11 best-known, 198.97us): 128x128 tile, 4 waves (2M x 2N),
// per-wave 64x64, BK=64, single-buffered 32KB LDS, XOR bank-swizzle
// (both sides), plain __syncthreads, __launch_bounds__(256,4).
// LAUNCH BOUNDS RULE (R8+R12 spills): never cap VGPR below 128.
// MFMA RULE (R14): keep 16x16x32 — the 32x32x16 fragment pattern
// degrades the XOR swizzle to 4-way ds_read conflicts (6.3e6) and
// fragments epilogue stores (WRITE 49->71MB).
// ROWXCD (QKV): row-grouped XCD map (neutral, harmless).
// VSPLIT (QKV): cols n0>=2048 are V -> vt[b][d][s] transposed via
// non-swapped MFMA; else swapped MFMA (acc regs along N, vec4 C).
// EXPOUT (scores): C = exp(acc*scale) bf16 + per-WAVE partial row-sums
// into psum[b][row][bx*2+wn] (32 slots/row; private slot per wave).
// DIVSUM (PV): C = acc / sum(psum[b][row][0..32]).
// =====================================================================
template <typename OutT, bool HAS_BIAS, bool VSPLIT, bool EXPOUT, bool DIVSUM,
          bool ROWXCD>
__global__ __launch_bounds__(256, 4) void gemm_hi(
    const unsigned short* __restrict__ A,
    const unsigned short* __restrict__ Bt,
    OutT* __restrict__ C,
    const float* __restrict__ bias,   // bias | psum-base (DIVSUM)
    unsigned short* __restrict__ vt,  // Vt (VSPLIT)
    float* __restrict__ psum,         // partial row-sums (EXPOUT)
    int K, int lda, int ldb, int ldc, float scale,
    long sA, long sB, long sC) {
  int bx, by, bz;
  if constexpr (ROWXCD) {
    const int lin = blockIdx.x + 24 * blockIdx.y;
    const int xcd = lin & 7, idx = lin >> 3;  // idx in 0..191
    by = xcd + ((idx / 24) << 3);
    bx = idx % 24;
    bz = 0;
  } else {
    xcd_swz(bx, by, bz);
  }
  A  += (long)bz * sA;
  Bt += (long)bz * sB;
  C  += (long)bz * sC;
  const int n0 = bx << 7;
  const int m0 = by << 7;
  __shared__ __attribute__((aligned(16))) unsigned short As[128 * 64];
  __shared__ __attribute__((aligned(16))) unsigned short Bs[128 * 64];
  const int t = threadIdx.x;
  const int lane = t & 63;
  const int w = t >> 6;
  const int wm = w >> 1, wn = w & 1;
  const unsigned short* gA = A + (size_t)m0 * lda;
  const unsigned short* gB = Bt + (size_t)n0 * ldb;
  const int NT = K >> 6;

  const int srow = lane >> 3;
  const int scol = ((lane & 7) ^ srow) << 3;

  f32x4 acc[4][4];
  const f32x4 vz = {0.f, 0.f, 0.f, 0.f};
#pragma unroll
  for (int i = 0; i < 4; ++i)
#pragma unroll
    for (int j = 0; j < 4; ++j) acc[i][j] = vz;

  for (int kt = 0; kt < NT; ++kt) {
    const unsigned short* pA = gA + (size_t)kt * 64;
    const unsigned short* pB = gB + (size_t)kt * 64;
#pragma unroll
    for (int i = 0; i < 4; ++i) {
      const int r0 = (w << 3) + (i << 5);
      gload_lds16(pA + (size_t)(r0 + srow) * lda + scol, As + r0 * 64);
      gload_lds16(pB + (size_t)(r0 + srow) * ldb + scol, Bs + r0 * 64);
    }
    __syncthreads();

#pragma unroll
    for (int kk = 0; kk < 2; ++kk) {
      bf16x8 af[4], bg[4];
      const int ch = ((kk << 2) + (lane >> 4)) ^ (lane & 7);
#pragma unroll
      for (int m = 0; m < 4; ++m) {
        const int row = (wm << 6) + (m << 4) + (lane & 15);
        af[m] = *reinterpret_cast<const bf16x8*>(As + row * 64 + (ch << 3));
      }
#pragma unroll
      for (int n = 0; n < 4; ++n) {
        const int row = (wn << 6) + (n << 4) + (lane & 15);
        bg[n] = *reinterpret_cast<const bf16x8*>(Bs + row * 64 + (ch << 3));
      }
#pragma unroll
      for (int m = 0; m < 4; ++m)
#pragma unroll
        for (int n = 0; n < 4; ++n) {
          if constexpr (VSPLIT) {
            acc[m][n] = __builtin_amdgcn_mfma_f32_16x16x32_bf16(
                af[m], bg[n], acc[m][n], 0, 0, 0);
          } else {
            acc[m][n] = __builtin_amdgcn_mfma_f32_16x16x32_bf16(
                bg[n], af[m], acc[m][n], 0, 0, 0);
          }
        }
    }
    __syncthreads();
  }

  if constexpr (VSPLIT) {
    // non-swapped C/D: col = lane&15 (N), row = (lane>>4)*4 + i (M)
    const int crow0 = m0 + (wm << 6) + ((lane >> 4) << 2);
    const int ccol0 = n0 + (wn << 6) + (lane & 15);
    if (n0 >= 2048) {
      const int b = m0 >> 11;
#pragma unroll
      for (int mf = 0; mf < 4; ++mf) {
#pragma unroll
        for (int nf = 0; nf < 4; ++nf) {
          const int col = ccol0 + (nf << 4);
          const float bb = HAS_BIAS ? bias[col] : 0.f;
          const int d = col - 2048;
          const int s = (crow0 & 2047) + (mf << 4);
          ushort4 o;
          o.x = f2bf(acc[mf][nf][0] * scale + bb);
          o.y = f2bf(acc[mf][nf][1] * scale + bb);
          o.z = f2bf(acc[mf][nf][2] * scale + bb);
          o.w = f2bf(acc[mf][nf][3] * scale + bb);
          *reinterpret_cast<ushort4*>(
              vt + (((size_t)b << 10) + d) * 2048 + s) = o;
        }
      }
    } else {
#pragma unroll
      for (int mf = 0; mf < 4; ++mf) {
#pragma unroll
        for (int nf = 0; nf < 4; ++nf) {
          const int col = ccol0 + (nf << 4);
          const float bb = HAS_BIAS ? bias[col] : 0.f;
#pragma unroll
          for (int i = 0; i < 4; ++i) {
            const int row = crow0 + (mf << 4) + i;
            C[(size_t)row * ldc + col] =
                (OutT)f2bf(acc[mf][nf][i] * scale + bb);
          }
        }
      }
    }
  } else {
    // swapped C/D: row = lane&15 (M), regs = 4 consecutive N
    const int mrow0 = m0 + (wm << 6) + (lane & 15);
    const int ncol0 = n0 + (wn << 6) + ((lane >> 4) << 2);
#pragma unroll
    for (int mf = 0; mf < 4; ++mf) {
      const int row = mrow0 + (mf << 4);
      float inv = 1.f;
      if constexpr (DIVSUM) {
        const float* pr = bias + ((long)bz * 2048 + row) * 32;
        float s = 0.f;
#pragma unroll
        for (int q = 0; q < 8; ++q) {
          const float4 sv = *reinterpret_cast<const float4*>(pr + q * 4);
          s += (sv.x + sv.y) + (sv.z + sv.w);
        }
        inv = 1.f / s;
      }
      float ps = 0.f;
#pragma unroll
      for (int nf = 0; nf < 4; ++nf) {
        const int col = ncol0 + (nf << 4);
        const f32x4 a = acc[mf][nf];
        if constexpr (EXPOUT) {
          const float e0 = __expf(a[0] * scale);
          const float e1 = __expf(a[1] * scale);
          const float e2 = __expf(a[2] * scale);
          const float e3 = __expf(a[3] * scale);
          ps += (e0 + e1) + (e2 + e3);
          ushort4 o;
          o.x = f2bf(e0); o.y = f2bf(e1); o.z = f2bf(e2); o.w = f2bf(e3);
          *reinterpret_cast<ushort4*>(&C[(size_t)row * ldc + col]) = o;
        } else if constexpr (DIVSUM) {
          ushort4 o;
          o.x = f2bf(a[0] * inv);
          o.y = f2bf(a[1] * inv);
          o.z = f2bf(a[2] * inv);
          o.w = f2bf(a[3] * inv);
          *reinterpret_cast<ushort4*>(&C[(size_t)row * ldc + col]) = o;
        } else {
          float4 bb = {0.f, 0.f, 0.f, 0.f};
          if (HAS_BIAS) bb = *reinterpret_cast<const float4*>(bias + col);
          if constexpr (sizeof(OutT) == 2) {
            ushort4 o;
            o.x = f2bf(a[0] * scale + bb.x);
            o.y = f2bf(a[1] * scale + bb.y);
            o.z = f2bf(a[2] * scale + bb.z);
            o.w = f2bf(a[3] * scale + bb.w);
            *reinterpret_cast<ushort4*>(&C[(size_t)row * ldc + col]) = o;
          } else {
            float4 o;
            o.x = a[0] * scale + bb.x;
            o.y = a[1] * scale + bb.y;
            o.z = a[2] * scale + bb.z;
            o.w = a[3] * scale + bb.w;
            *reinterpret_cast<float4*>(&C[(size_t)row * ldc + col]) = o;
          }
        }
      }
      if constexpr (EXPOUT) {
        // reduce across the 4 lane-groups of THIS wave (64 cols);
        // each wn wave stores its own slot (32 slots/row).
        ps += __shfl_xor(ps, 16, 64);
        ps += __shfl_xor(ps, 32, 64);
        if ((lane >> 4) == 0)
          psum[((long)bz * 2048 + row) * 32 + (bx << 1) + wn] = ps;
      }
    }
  }
}

// ---------- launch ----------
extern "C" void kernel_launch(void* const* d_in, const int* in_sizes, int n_in,
                              void* d_out, int out_size, void* d_ws, size_t ws_size,
                              hipStream_t stream) {
  (void)in_sizes; (void)n_in; (void)out_size; (void)ws_size;
  const float* x  = (const float*)d_in[0];
  const float* Wq = (const float*)d_in[1];
  const float* bq = (const float*)d_in[2];
  const float* Wk = (const float*)d_in[3];
  const float* bk = (const float*)d_in[4];
  const float* Wv = (const float*)d_in[5];
  const float* bv = (const float*)d_in[6];
  const float* Wo = (const float*)d_in[7];
  const float* bo = (const float*)d_in[8];
  float* out = (float*)d_out;

  constexpr int B = 4, S = 2048, D = 1024;
  constexpr long BS = (long)B * S;  // 8192
  constexpr size_t MB = 1ull << 20;
  char* ws = (char*)d_ws;
  unsigned short* xb   = (unsigned short*)(ws + 0);        // 16MB (dead after QKV)
  unsigned short* Wall = (unsigned short*)(ws + 16 * MB);  // 8MB [4][1024][1024]
  float*          bqkv = (float*)(ws + 24 * MB);           // 12KB
  float*          psum = (float*)(ws + 24 * MB + 65536);   // 1MB [4][2048][32]
  unsigned short* QKVc = (unsigned short*)(ws + 26 * MB);  // 32MB [8192][2048] Q|K
  unsigned short* Vt   = (unsigned short*)(ws + 58 * MB);  // 16MB [4][1024][2048]
  unsigned short* Sc   = (unsigned short*)(ws + 74 * MB);  // 32MB exp-scores
  unsigned short* AO   = (unsigned short*)(ws + 0);        // 16MB (over xb)

  const float scale = 0.03125f;  // 1/sqrt(1024)

  cvt_f32_to_bf16<<<(BS * D / 4 + 255) / 256, 256, 0, stream>>>(x, xb, BS * D / 4);
  transpose_w4<<<dim3(32, 32, 4), dim3(32, 32), 0, stream>>>(
      Wq, Wk, Wv, Wo, bq, bk, bv, Wall, bqkv);

  // fused QKV projection (row-grouped XCD map): Q|K -> QKVc, V -> Vt^T
  gemm_hi<unsigned short, true, true, false, false, true>
      <<<dim3(24, 64, 1), 256, 0, stream>>>(
      xb, Wall, QKVc, bqkv, Vt, nullptr, D, D, D, 2048, 1.f, 0, 0, 0);

  // exp-scores[b] = exp(scale * Q@K^T); per-wave partial row-sums -> psum
  gemm_hi<unsigned short, false, false, true, false, false>
      <<<dim3(16, 16, 4), 256, 0, stream>>>(
      QKVc + 0, QKVc + 1024, Sc, nullptr, nullptr, psum, D, 2048, 2048, S,
      scale, (long)S * 2048, (long)S * 2048, (long)S * S);

  // attn_out[b] = (expS[b] @ V[b]) / rowsum  via Vt
  gemm_hi<unsigned short, false, false, false, true, false>
      <<<dim3(8, 16, 4), 256, 0, stream>>>(
      Sc, Vt, AO, psum, nullptr, nullptr, S, S, S, D, 1.f,
      (long)S * S, (long)D * S, (long)S * D);

  // out = AO @ Wot^T + bo (fp32)
  gemm_hi<float, true, false, false, false, false>
      <<<dim3(8, 64, 1), 256, 0, stream>>>(
      AO, Wall + 3 * 1024 * 1024, out, bo, nullptr, nullptr, D, D, D, D, 1.f,
      0, 0, 0);
}